// Round 10
// baseline (161.094 us; speedup 1.0000x reference)
//
#include <hip/hip_runtime.h>
#include <hip/hip_fp16.h>

#define N_DET 128
#define N_T   2048
#define NPIX  65536   // 256*256

typedef float f4_t __attribute__((ext_vector_type(4)));
typedef f4_t __attribute__((aligned(8))) f4a8_t;

// Kernel 1: transpose+pack sino (B, N_DET, N_T) fp32 -> ws (N_DET, N_T) of
// 8-byte records { s_t[b0..b3] } as 4 fp16 (ws = 2 MB, L2-resident).
__global__ __launch_bounds__(256) void sino_pack_kernel(
    const float* __restrict__ sino, float2* __restrict__ ws) {
  const int idx = blockIdx.x * blockDim.x + threadIdx.x;  // idx = d*N_T + t
  const __half2 lo = __floats2half2_rn(
      __builtin_nontemporal_load(sino + 0 * N_DET * N_T + idx),
      __builtin_nontemporal_load(sino + 1 * N_DET * N_T + idx));
  const __half2 hi = __floats2half2_rn(
      __builtin_nontemporal_load(sino + 2 * N_DET * N_T + idx),
      __builtin_nontemporal_load(sino + 3 * N_DET * N_T + idx));
  union { struct { __half2 a, b; } h; float2 f; } u;
  u.h.a = lo;
  u.h.b = hi;
  ws[idx] = u.f;
}

// Kernel 2: direct-L2 gather, no LDS staging / barriers / atomics.
// Thread = (pixel, det-quarter): 65536 px x 4 quarters = 262144 threads
// (1024 blocks -> 4 blocks/CU, 16 waves/CU). Each thread loops 8 chunks of
// 4 dets: 2 NT lut dwordx4 + 4 independent 16B gathers from the 2 MB
// L2-resident packed ws (one gather per (px,det): taps t,t+1 x 4 batches).
// lut is fully line-utilized (thread reads its contiguous 256 B over the
// loop) and non-temporal so the 64 MB stream never evicts ws from L2.
__global__ __launch_bounds__(256, 4) void das_l2_kernel(
    const float* __restrict__ lut, const unsigned char* __restrict__ S8,
    float* __restrict__ out) {
  __shared__ float apod_s[N_DET];
  const int tid = threadIdx.x;
  if (tid < N_DET) {
    apod_s[tid] = 0.5f - 0.5f * cosf(6.28318530717958647692f *
                                     ((float)tid / (float)(N_DET - 1)));
  }
  __syncthreads();

  const int q = tid & 3;                       // det quarter (32 dets)
  const int p = blockIdx.x * 64 + (tid >> 2);  // pixel
  const int d0 = q * 32;
  const f4_t* lutp =
      reinterpret_cast<const f4_t*>(lut + ((size_t)p * N_DET + d0) * 2);

  float a0 = 0.f, a1 = 0.f, a2 = 0.f, a3 = 0.f;

#pragma unroll 1
  for (int c = 0; c < 8; ++c) {  // 8 chunks x 4 dets
    const f4_t l0 = __builtin_nontemporal_load(lutp + c * 2);      // d+0,d+1
    const f4_t l1 = __builtin_nontemporal_load(lutp + c * 2 + 1);  // d+2,d+3
    const float tofs[4] = {l0.x, l0.z, l1.x, l1.z};
    const float als[4]  = {l0.y, l0.w, l1.y, l1.w};

    // Issue all 4 gathers first (independent -> 4 outstanding VMEM).
    f4_t v[4];
    float kf[4];
#pragma unroll
    for (int j = 0; j < 4; ++j) {
      kf[j] = floorf(tofs[j]);
      const int k0 = (int)fminf(fmaxf(kf[j], 0.0f), (float)(N_T - 2));
      const unsigned voff =
          (((unsigned)(d0 + c * 4 + j) << 11) + (unsigned)k0) * 8u;
      v[j] = *reinterpret_cast<const f4a8_t*>(S8 + voff);  // 16B: t,t+1 x 4b
    }

#pragma unroll
    for (int j = 0; j < 4; ++j) {
      const bool valid = (kf[j] >= 0.0f) && (kf[j] < (float)(N_T - 1));
      const float w = valid ? apod_s[d0 + c * 4 + j] : 0.0f;
      const float al = als[j];
      const __half2* hp = reinterpret_cast<const __half2*>(&v[j]);
      const float2 s0a = __half22float2(hp[0]);  // t:   b0,b1
      const float2 s0b = __half22float2(hp[1]);  // t:   b2,b3
      const float2 s1a = __half22float2(hp[2]);  // t+1: b0,b1
      const float2 s1b = __half22float2(hp[3]);  // t+1: b2,b3
      a0 += w * (s0a.x + al * (s1a.x - s0a.x));
      a1 += w * (s0a.y + al * (s1a.y - s0a.y));
      a2 += w * (s0b.x + al * (s1b.x - s0b.x));
      a3 += w * (s0b.y + al * (s1b.y - s0b.y));
    }
  }

  // Reduce the 4 det-quarters (consecutive lanes) via quad shuffles.
  a0 += __shfl_xor(a0, 1);  a0 += __shfl_xor(a0, 2);
  a1 += __shfl_xor(a1, 1);  a1 += __shfl_xor(a1, 2);
  a2 += __shfl_xor(a2, 1);  a2 += __shfl_xor(a2, 2);
  a3 += __shfl_xor(a3, 1);  a3 += __shfl_xor(a3, 2);

  if (q == 0) {  // lanes 0,4,..,60 -> 16 consecutive pixels per batch plane
    const float nrm = 1.0f / 63.5f;  // sum(apod) == 63.5 analytically
    __builtin_nontemporal_store(a0 * nrm, out + 0 * NPIX + p);
    __builtin_nontemporal_store(a1 * nrm, out + 1 * NPIX + p);
    __builtin_nontemporal_store(a2 * nrm, out + 2 * NPIX + p);
    __builtin_nontemporal_store(a3 * nrm, out + 3 * NPIX + p);
  }
}

// Fallback (no workspace): direct fp32 gather from original layout.
__global__ __launch_bounds__(256) void das_fallback_kernel(
    const float* __restrict__ lut, const float* __restrict__ S,
    float* __restrict__ out) {
  const int lane = threadIdx.x & 63;
  const int p = blockIdx.x * 4 + (threadIdx.x >> 6);

  const float4 lv =
      reinterpret_cast<const float4*>(lut + (size_t)p * 2 * N_DET)[lane];

  float acc0 = 0.f, acc1 = 0.f, acc2 = 0.f, acc3 = 0.f;
  float wsum = 0.f;

#pragma unroll
  for (int j = 0; j < 2; ++j) {
    const int d = 2 * lane + j;
    const float tof = j ? lv.z : lv.x;
    const float a   = j ? lv.w : lv.y;
    const float kf = floorf(tof);
    const bool valid = (kf >= 0.0f) && (kf < (float)(N_T - 1));
    const float kcl = fminf(fmaxf(kf, 0.0f), (float)(N_T - 2));
    const int k0 = (int)kcl;
    const float apd =
        0.5f - 0.5f * cosf(6.28318530717958647692f *
                           (1.0f / (float)(N_DET - 1)) * (float)d);
    wsum += apd;
    const float w = valid ? apd : 0.0f;
    const float om = 1.0f - a;
    const float* row = S + (size_t)d * N_T + k0;
    acc0 += w * (om * row[0 * N_DET * N_T] + a * row[0 * N_DET * N_T + 1]);
    acc1 += w * (om * row[1 * N_DET * N_T] + a * row[1 * N_DET * N_T + 1]);
    acc2 += w * (om * row[2 * N_DET * N_T] + a * row[2 * N_DET * N_T + 1]);
    acc3 += w * (om * row[3 * N_DET * N_T] + a * row[3 * N_DET * N_T + 1]);
  }

#pragma unroll
  for (int off = 32; off > 0; off >>= 1) {
    acc0 += __shfl_xor(acc0, off);
    acc1 += __shfl_xor(acc1, off);
    acc2 += __shfl_xor(acc2, off);
    acc3 += __shfl_xor(acc3, off);
    wsum += __shfl_xor(wsum, off);
  }

  if (lane == 0) {
    const float inv = 1.0f / fmaxf(wsum, 1.17549435e-38f);
    out[0 * NPIX + p] = acc0 * inv;
    out[1 * NPIX + p] = acc1 * inv;
    out[2 * NPIX + p] = acc2 * inv;
    out[3 * NPIX + p] = acc3 * inv;
  }
}

extern "C" void kernel_launch(void* const* d_in, const int* in_sizes, int n_in,
                              void* d_out, int out_size, void* d_ws, size_t ws_size,
                              hipStream_t stream) {
  const float* sino = (const float*)d_in[0];  // (B,1,N_DET,N_T) fp32
  const float* lut  = (const float*)d_in[1];  // (NY,NX,N_DET,2) fp32
  float* out = (float*)d_out;                 // (B,1,NY,NX) fp32

  const size_t need = (size_t)N_DET * N_T * 8;  // 2 MB packed ws
  if (ws_size >= need) {
    float2* ws = (float2*)d_ws;
    sino_pack_kernel<<<(N_DET * N_T) / 256, 256, 0, stream>>>(sino, ws);
    das_l2_kernel<<<NPIX / 64, 256, 0, stream>>>(
        lut, (const unsigned char*)d_ws, out);
  } else {
    das_fallback_kernel<<<NPIX / 4, 256, 0, stream>>>(lut, sino, out);
  }
}